// Round 4
// baseline (337.060 us; speedup 1.0000x reference)
//
#include <hip/hip_runtime.h>
#include <math.h>

namespace {

constexpr int B_ = 4, N_ = 4, C_ = 64, H_ = 128, W_ = 128;
constexpr int HW_ = H_ * W_;

// out[:, 4] = ref
__global__ __launch_bounds__(256) void copyref_kernel(const float* __restrict__ ref,
                                                      float* __restrict__ out) {
    int t = blockIdx.x * 256 + threadIdx.x;      // one float4 per thread
    int f = t * 4;
    int b = f / (C_ * HW_);
    int within = f - b * (C_ * HW_);
    float4 v = *reinterpret_cast<const float4*>(ref + (size_t)b * C_ * HW_ + within);
    *reinterpret_cast<float4*>(out + (size_t)(b * 5 + N_) * C_ * HW_ + within) = v;
}

// Main kernel: lane-quad C-split, one row per 128-thread block.
//   thread -> (pixel-group of 4 consecutive x, channel-chunk q of 16 channels)
//   q = tid & 3 -> the 4 partial reducers are adjacent lanes (shfl_xor width-4 reduce)
//   grid = B*N*H = 2048 blocks; XCD-swizzled so image bi lives on XCD bi>>1.
__global__ __launch_bounds__(128, 8) void localcorr_kernel(const float* __restrict__ nbrs,
                                                           const float* __restrict__ ref,
                                                           float* __restrict__ out) {
    // XCD-aware bijective remap: blockIdx round-robins XCDs (blk&7 -> XCD),
    // so give XCD x the two images bi = 2x, 2x+1 (same b -> shared ref rows).
    const int s = blockIdx.x;            // 0..2047
    const int j = s >> 3;                // 0..255
    const int bi = (s & 7) * 2 + (j >> 7);
    const int y = j & 127;
    const int i = bi & 3;
    const int b = bi >> 2;
    const int tid = (int)threadIdx.x;    // 0..127
    const int q = tid & 3;               // channel chunk
    const int g = tid >> 2;              // pixel group 0..31
    const int xb = g * 4;
    const int c0 = q * 16;

    // reflect-pad (np 'reflect', pad=1): idx -1 -> 1, idx W -> W-2
    const int ym1 = (y == 0) ? 1 : y - 1;
    const int yp1 = (y == H_ - 1) ? H_ - 2 : y + 1;
    const int xm1 = (xb == 0) ? 1 : xb - 1;
    const int xp4 = (xb + 4 == W_) ? W_ - 2 : xb + 4;

    const int ro0 = ym1 * W_, ro1 = y * W_, ro2 = yp1 * W_;

    const float* __restrict__ nb = nbrs + (size_t)(b * N_ + i) * C_ * HW_;
    const float* __restrict__ rp = ref + (size_t)b * C_ * HW_ + y * W_ + xb;

    float dot[9][4];     // partial dots over this thread's 16 channels
    float nrm2[3][6];    // partial sq-norms, 3 rows x 6 cols (xb-1 .. xb+4)
    float ref2[4];       // partial ref sq-norms
#pragma unroll
    for (int k = 0; k < 9; ++k)
#pragma unroll
        for (int jj = 0; jj < 4; ++jj) dot[k][jj] = 0.f;
#pragma unroll
    for (int r = 0; r < 3; ++r)
#pragma unroll
        for (int m = 0; m < 6; ++m) nrm2[r][m] = 0.f;
#pragma unroll
    for (int jj = 0; jj < 4; ++jj) ref2[jj] = 0.f;

    // ---- pass 1 over this thread's channels: raw dots + squared norms ----
    for (int cc = 0; cc < 16; ++cc) {
        const int c = c0 + cc;
        const float* pc = nb + c * HW_;
        const float4 rv = *reinterpret_cast<const float4*>(rp + c * HW_);
        const float r4[4] = {rv.x, rv.y, rv.z, rv.w};
#pragma unroll
        for (int jj = 0; jj < 4; ++jj) ref2[jj] += r4[jj] * r4[jj];
        const int ros[3] = {ro0, ro1, ro2};
#pragma unroll
        for (int r = 0; r < 3; ++r) {
            const float* row = pc + ros[r];
            const float4 m4 = *reinterpret_cast<const float4*>(row + xb);
            const float v[6] = {row[xm1], m4.x, m4.y, m4.z, m4.w, row[xp4]};
#pragma unroll
            for (int m = 0; m < 6; ++m) nrm2[r][m] += v[m] * v[m];
#pragma unroll
            for (int dx = 0; dx < 3; ++dx) {
#pragma unroll
                for (int jj = 0; jj < 4; ++jj) dot[r * 3 + dx][jj] += r4[jj] * v[jj + dx];
            }
        }
    }

    // ---- reduce partials across the 4 chunk-lanes (width-4 butterfly) ----
#pragma unroll
    for (int k = 0; k < 9; ++k)
#pragma unroll
        for (int jj = 0; jj < 4; ++jj) {
            float v = dot[k][jj];
            v += __shfl_xor(v, 1, 4);
            v += __shfl_xor(v, 2, 4);
            dot[k][jj] = v;
        }
#pragma unroll
    for (int r = 0; r < 3; ++r)
#pragma unroll
        for (int m = 0; m < 6; ++m) {
            float v = nrm2[r][m];
            v += __shfl_xor(v, 1, 4);
            v += __shfl_xor(v, 2, 4);
            nrm2[r][m] = v;
        }
#pragma unroll
    for (int jj = 0; jj < 4; ++jj) {
        float v = ref2[jj];
        v += __shfl_xor(v, 1, 4);
        v += __shfl_xor(v, 2, 4);
        ref2[jj] = v;
    }

    // ---- normalize, softmax over 9 neighbors per pixel (redundant in 4 lanes) ----
    float invn[3][6];
#pragma unroll
    for (int r = 0; r < 3; ++r)
#pragma unroll
        for (int m = 0; m < 6; ++m) invn[r][m] = rsqrtf(fmaxf(nrm2[r][m], 1e-24f));

    float wtp[9][4];     // softmax weight * inv-norm of that neighbor (folded)
#pragma unroll
    for (int jj = 0; jj < 4; ++jj) {
        const float invr = rsqrtf(fmaxf(ref2[jj], 1e-24f));
        float d[9];
#pragma unroll
        for (int r = 0; r < 3; ++r)
#pragma unroll
            for (int dx = 0; dx < 3; ++dx)
                d[r * 3 + dx] = dot[r * 3 + dx][jj] * invr * invn[r][jj + dx];
        float mx = d[0];
#pragma unroll
        for (int k = 1; k < 9; ++k) mx = fmaxf(mx, d[k]);
        float e[9], ssum = 0.f;
#pragma unroll
        for (int k = 0; k < 9; ++k) { e[k] = __expf(d[k] - mx); ssum += e[k]; }
        const float is = 1.f / ssum;
#pragma unroll
        for (int r = 0; r < 3; ++r)
#pragma unroll
            for (int dx = 0; dx < 3; ++dx)
                wtp[r * 3 + dx][jj] = e[r * 3 + dx] * is * invn[r][jj + dx];
    }

    // ---- pass 2 over this thread's channels: aggregate + wdiff + store ----
    const float* __restrict__ nbb = nbrs + (size_t)b * N_ * C_ * HW_;
    float* __restrict__ op = out + (size_t)(b * 5 + i) * C_ * HW_ + y * W_ + xb;
    for (int cc = 0; cc < 16; ++cc) {
        const int c = c0 + cc;
        const float* pc = nb + c * HW_;
        float agg[4] = {0.f, 0.f, 0.f, 0.f};
        float ctr[4] = {0.f, 0.f, 0.f, 0.f};
        const int ros[3] = {ro0, ro1, ro2};
#pragma unroll
        for (int r = 0; r < 3; ++r) {
            const float* row = pc + ros[r];
            const float4 m4 = *reinterpret_cast<const float4*>(row + xb);
            const float v[6] = {row[xm1], m4.x, m4.y, m4.z, m4.w, row[xp4]};
#pragma unroll
            for (int dx = 0; dx < 3; ++dx) {
#pragma unroll
                for (int jj = 0; jj < 4; ++jj) agg[jj] += wtp[r * 3 + dx][jj] * v[jj + dx];
            }
            if (r == 1) {
#pragma unroll
                for (int jj = 0; jj < 4; ++jj) ctr[jj] = v[jj + 1];
            }
        }
        // mean over the 4 neighbor images; own image's center row is already in ctr
        float s4[4] = {ctr[0], ctr[1], ctr[2], ctr[3]};
#pragma unroll
        for (int ii = 0; ii < N_; ++ii) {
            if (ii == i) continue;   // block-uniform branch
            const float4 qv = *reinterpret_cast<const float4*>(nbb + (size_t)(ii * C_ + c) * HW_ + ro1 + xb);
            s4[0] += qv.x; s4[1] += qv.y; s4[2] += qv.z; s4[3] += qv.w;
        }
        float o[4];
#pragma unroll
        for (int jj = 0; jj < 4; ++jj) {
            const float dd = ctr[jj] - 0.25f * s4[jj];
            o[jj] = agg[jj] * __expf(-dd * dd);
        }
        float4 o4; o4.x = o[0]; o4.y = o[1]; o4.z = o[2]; o4.w = o[3];
        *reinterpret_cast<float4*>(op + c * HW_) = o4;
    }
}

}  // namespace

extern "C" void kernel_launch(void* const* d_in, const int* in_sizes, int n_in,
                              void* d_out, int out_size, void* d_ws, size_t ws_size,
                              hipStream_t stream) {
    const float* nbrs = (const float*)d_in[0];
    const float* ref = (const float*)d_in[1];
    float* out = (float*)d_out;

    // slot 4 = ref copy: B*C*HW floats / 4 per thread / 256 per block
    copyref_kernel<<<(B_ * C_ * HW_ / 4) / 256, 256, 0, stream>>>(ref, out);

    // main: B*N*H = 2048 one-row blocks of 128 threads
    localcorr_kernel<<<B_ * N_ * H_, 128, 0, stream>>>(nbrs, ref, out);
}

// Round 6
// 322.142 us; speedup vs baseline: 1.0463x; 1.0463x over previous
//
#include <hip/hip_runtime.h>
#include <math.h>

namespace {

constexpr int B_ = 4, N_ = 4, C_ = 64, H_ = 128, W_ = 128;
constexpr int HW_ = H_ * W_;

// out[:, 4] = ref
__global__ __launch_bounds__(256) void copyref_kernel(const float* __restrict__ ref,
                                                      float* __restrict__ out) {
    int t = blockIdx.x * 256 + threadIdx.x;      // one float4 per thread
    int f = t * 4;
    int b = f / (C_ * HW_);
    int within = f - b * (C_ * HW_);
    float4 v = *reinterpret_cast<const float4*>(ref + (size_t)b * C_ * HW_ + within);
    *reinterpret_cast<float4*>(out + (size_t)(b * 5 + N_) * C_ * HW_ + within) = v;
}

// Main kernel: lane-octet C-split, one row per 256-thread block.
//   thread -> (pixel-group of 4 consecutive x, channel-chunk q of 8 channels)
//   q = tid & 7 -> the 8 partial reducers are adjacent lanes (shfl_xor width-8 reduce)
//   grid = B*N*H = 2048 blocks x 4 waves = 8192 waves = 100% nominal occupancy.
//   XCD-swizzled: image bi -> XCD bi>>1 (2 images per XCD, same b shares ref).
__global__ __launch_bounds__(256, 4) void localcorr_kernel(const float* __restrict__ nbrs,
                                                           const float* __restrict__ ref,
                                                           float* __restrict__ out) {
    const int s = blockIdx.x;            // 0..2047
    const int j = s >> 3;                // 0..255
    const int bi = (s & 7) * 2 + (j >> 7);
    const int y = j & 127;
    const int i = bi & 3;
    const int b = bi >> 2;
    const int tid = (int)threadIdx.x;    // 0..255
    const int q = tid & 7;               // channel chunk (8 channels each)
    const int g = tid >> 3;              // pixel group 0..31
    const int xb = g * 4;
    const int c0 = q * 8;

    // reflect-pad (np 'reflect', pad=1): idx -1 -> 1, idx W -> W-2
    const int ym1 = (y == 0) ? 1 : y - 1;
    const int yp1 = (y == H_ - 1) ? H_ - 2 : y + 1;
    const int xm1 = (xb == 0) ? 1 : xb - 1;
    const int xp4 = (xb + 4 == W_) ? W_ - 2 : xb + 4;

    const int ro0 = ym1 * W_, ro1 = y * W_, ro2 = yp1 * W_;

    const float* __restrict__ nb = nbrs + (size_t)(b * N_ + i) * C_ * HW_;
    const float* __restrict__ rp = ref + (size_t)b * C_ * HW_ + y * W_ + xb;

    float dot[9][4];     // partial dots over this thread's 8 channels
    float nrm2[3][6];    // partial sq-norms, 3 rows x 6 cols (xb-1 .. xb+4)
    float ref2[4];       // partial ref sq-norms
#pragma unroll
    for (int k = 0; k < 9; ++k)
#pragma unroll
        for (int jj = 0; jj < 4; ++jj) dot[k][jj] = 0.f;
#pragma unroll
    for (int r = 0; r < 3; ++r)
#pragma unroll
        for (int m = 0; m < 6; ++m) nrm2[r][m] = 0.f;
#pragma unroll
    for (int jj = 0; jj < 4; ++jj) ref2[jj] = 0.f;

    // ---- pass 1 over this thread's channels: raw dots + squared norms ----
    for (int cc = 0; cc < 8; ++cc) {
        const int c = c0 + cc;
        const float* pc = nb + c * HW_;
        const float4 rv = *reinterpret_cast<const float4*>(rp + c * HW_);
        const float r4[4] = {rv.x, rv.y, rv.z, rv.w};
#pragma unroll
        for (int jj = 0; jj < 4; ++jj) ref2[jj] += r4[jj] * r4[jj];
        const int ros[3] = {ro0, ro1, ro2};
#pragma unroll
        for (int r = 0; r < 3; ++r) {
            const float* row = pc + ros[r];
            const float4 m4 = *reinterpret_cast<const float4*>(row + xb);
            const float v[6] = {row[xm1], m4.x, m4.y, m4.z, m4.w, row[xp4]};
#pragma unroll
            for (int m = 0; m < 6; ++m) nrm2[r][m] += v[m] * v[m];
#pragma unroll
            for (int dx = 0; dx < 3; ++dx) {
#pragma unroll
                for (int jj = 0; jj < 4; ++jj) dot[r * 3 + dx][jj] += r4[jj] * v[jj + dx];
            }
        }
    }

    // ---- reduce partials across the 8 chunk-lanes (width-8 butterfly) ----
#pragma unroll
    for (int k = 0; k < 9; ++k)
#pragma unroll
        for (int jj = 0; jj < 4; ++jj) {
            float v = dot[k][jj];
            v += __shfl_xor(v, 1, 8);
            v += __shfl_xor(v, 2, 8);
            v += __shfl_xor(v, 4, 8);
            dot[k][jj] = v;
        }
#pragma unroll
    for (int r = 0; r < 3; ++r)
#pragma unroll
        for (int m = 0; m < 6; ++m) {
            float v = nrm2[r][m];
            v += __shfl_xor(v, 1, 8);
            v += __shfl_xor(v, 2, 8);
            v += __shfl_xor(v, 4, 8);
            nrm2[r][m] = v;
        }
#pragma unroll
    for (int jj = 0; jj < 4; ++jj) {
        float v = ref2[jj];
        v += __shfl_xor(v, 1, 8);
        v += __shfl_xor(v, 2, 8);
        v += __shfl_xor(v, 4, 8);
        ref2[jj] = v;
    }

    // ---- normalize, softmax over 9 neighbors per pixel (redundant in 8 lanes) ----
    float invn[3][6];
#pragma unroll
    for (int r = 0; r < 3; ++r)
#pragma unroll
        for (int m = 0; m < 6; ++m) invn[r][m] = rsqrtf(fmaxf(nrm2[r][m], 1e-24f));

    float wtp[9][4];     // softmax weight * inv-norm of that neighbor (folded)
#pragma unroll
    for (int jj = 0; jj < 4; ++jj) {
        const float invr = rsqrtf(fmaxf(ref2[jj], 1e-24f));
        float d[9];
#pragma unroll
        for (int r = 0; r < 3; ++r)
#pragma unroll
            for (int dx = 0; dx < 3; ++dx)
                d[r * 3 + dx] = dot[r * 3 + dx][jj] * invr * invn[r][jj + dx];
        float mx = d[0];
#pragma unroll
        for (int k = 1; k < 9; ++k) mx = fmaxf(mx, d[k]);
        float e[9], ssum = 0.f;
#pragma unroll
        for (int k = 0; k < 9; ++k) { e[k] = __expf(d[k] - mx); ssum += e[k]; }
        const float is = 1.f / ssum;
#pragma unroll
        for (int r = 0; r < 3; ++r)
#pragma unroll
            for (int dx = 0; dx < 3; ++dx)
                wtp[r * 3 + dx][jj] = e[r * 3 + dx] * is * invn[r][jj + dx];
    }

    // ---- pass 2 over this thread's channels: aggregate + wdiff + store ----
    const float* __restrict__ nbb = nbrs + (size_t)b * N_ * C_ * HW_;
    float* __restrict__ op = out + (size_t)(b * 5 + i) * C_ * HW_ + y * W_ + xb;
    for (int cc = 0; cc < 8; ++cc) {
        const int c = c0 + cc;
        const float* pc = nb + c * HW_;
        float agg[4] = {0.f, 0.f, 0.f, 0.f};
        float ctr[4] = {0.f, 0.f, 0.f, 0.f};
        const int ros[3] = {ro0, ro1, ro2};
#pragma unroll
        for (int r = 0; r < 3; ++r) {
            const float* row = pc + ros[r];
            const float4 m4 = *reinterpret_cast<const float4*>(row + xb);
            const float v[6] = {row[xm1], m4.x, m4.y, m4.z, m4.w, row[xp4]};
#pragma unroll
            for (int dx = 0; dx < 3; ++dx) {
#pragma unroll
                for (int jj = 0; jj < 4; ++jj) agg[jj] += wtp[r * 3 + dx][jj] * v[jj + dx];
            }
            if (r == 1) {
#pragma unroll
                for (int jj = 0; jj < 4; ++jj) ctr[jj] = v[jj + 1];
            }
        }
        // mean over the 4 neighbor images; own image's center row is already in ctr
        float s4[4] = {ctr[0], ctr[1], ctr[2], ctr[3]};
#pragma unroll
        for (int ii = 0; ii < N_; ++ii) {
            if (ii == i) continue;   // block-uniform branch
            const float4 qv = *reinterpret_cast<const float4*>(nbb + (size_t)(ii * C_ + c) * HW_ + ro1 + xb);
            s4[0] += qv.x; s4[1] += qv.y; s4[2] += qv.z; s4[3] += qv.w;
        }
        float o[4];
#pragma unroll
        for (int jj = 0; jj < 4; ++jj) {
            const float dd = ctr[jj] - 0.25f * s4[jj];
            o[jj] = agg[jj] * __expf(-dd * dd);
        }
        float4 o4; o4.x = o[0]; o4.y = o[1]; o4.z = o[2]; o4.w = o[3];
        *reinterpret_cast<float4*>(op + c * HW_) = o4;
    }
}

}  // namespace

extern "C" void kernel_launch(void* const* d_in, const int* in_sizes, int n_in,
                              void* d_out, int out_size, void* d_ws, size_t ws_size,
                              hipStream_t stream) {
    const float* nbrs = (const float*)d_in[0];
    const float* ref = (const float*)d_in[1];
    float* out = (float*)d_out;

    // slot 4 = ref copy: B*C*HW floats / 4 per thread / 256 per block
    copyref_kernel<<<(B_ * C_ * HW_ / 4) / 256, 256, 0, stream>>>(ref, out);

    // main: B*N*H = 2048 one-row blocks of 256 threads
    localcorr_kernel<<<B_ * N_ * H_, 256, 0, stream>>>(nbrs, ref, out);
}